// Round 3
// 365.249 us; speedup vs baseline: 1.1993x; 1.1993x over previous
//
#include <hip/hip_runtime.h>
#include <hip/hip_bf16.h>
#include <cstdint>

#define HWP    4096
#define CDIM   256
#define KCODES 8192
#define NROWS  32768
#define SPLITS 8           // code-splits; split = bid & 7 -> one split per XCD
#define CPB    1024        // codes per block = KCODES / SPLITS
#define NSB    32          // sub-blocks of 32 codes per block

typedef _Float16 f16x8 __attribute__((ext_vector_type(8)));
typedef float    f32x4 __attribute__((ext_vector_type(4)));
typedef unsigned long long u64;

// ---- async global->LDS, 16B per lane; LDS dest = wave-uniform base + lane*16 ----
__device__ __forceinline__ void load16_to_lds(const void* g, void* s) {
    __builtin_amdgcn_global_load_lds(
        (const __attribute__((address_space(1))) void*)(uintptr_t)g,
        (__attribute__((address_space(3))) void*)(uintptr_t)s,
        16, 0, 0);
}

// u64 branch-free top-4 insert (for the tiny reduce kernel)
__device__ __forceinline__ void ins4(u64 c, u64 k[4]) {
    u64 a;
    a = k[0] > c ? k[0] : c;  c = k[0] > c ? c : k[0];  k[0] = a;
    a = k[1] > c ? k[1] : c;  c = k[1] > c ? c : k[1];  k[1] = a;
    a = k[2] > c ? k[2] : c;  c = k[2] > c ? c : k[2];  k[2] = a;
    k[3] = k[3] > c ? k[3] : c;
}

// =============== Kernel 1a: transpose x -> xh fp16 [N][C] + xt fp32 [N][C] ====
__global__ __launch_bounds__(256) void split_x_kernel(const float* __restrict__ x,
                                                      _Float16* __restrict__ xh,
                                                      float* __restrict__ xt) {
    __shared__ float tile[64][65];
    int pb = blockIdx.x, cbk = blockIdx.y, b = blockIdx.z;
    int t = threadIdx.x;
    int p0 = pb * 64, c0 = cbk * 64;
    int pl = t & 63, cl = t >> 6;
    const float* src = x + ((size_t)b * CDIM + c0) * HWP + p0;
    #pragma unroll 4
    for (int i = 0; i < 16; ++i) {
        int c = cl * 16 + i;
        tile[c][pl] = src[(size_t)c * HWP + pl];
    }
    __syncthreads();
    int p = t >> 2, cq = (t & 3) * 16;
    size_t n = (size_t)b * HWP + p0 + p;
    alignas(16) _Float16 hbuf[16];
    alignas(16) float    fbuf[16];
    #pragma unroll
    for (int j = 0; j < 16; ++j) {
        float v = tile[cq + j][p];
        fbuf[j] = v;
        hbuf[j] = (_Float16)v;
    }
    *(int4*)(xh + n * CDIM + c0 + cq)     = ((int4*)hbuf)[0];
    *(int4*)(xh + n * CDIM + c0 + cq + 8) = ((int4*)hbuf)[1];
    #pragma unroll
    for (int j = 0; j < 4; ++j)
        *(float4*)(xt + n * CDIM + c0 + cq + j * 4) = ((float4*)fbuf)[j];
}

// =============== Kernel 1b: convert codebook [K][C] -> fp16 ===================
__global__ __launch_bounds__(256) void split_cb_kernel(const float* __restrict__ cb,
                                                       _Float16* __restrict__ ch) {
    int i4 = blockIdx.x * 256 + threadIdx.x;          // 2048 blocks
    float4 v = ((const float4*)cb)[i4];
    alignas(8) _Float16 h[4];
    h[0] = (_Float16)v.x; h[1] = (_Float16)v.y;
    h[2] = (_Float16)v.z; h[3] = (_Float16)v.w;
    *(uint2*)(ch + (size_t)i4 * 4) = *(uint2*)h;
}

// =============== Kernel 2: A-in-registers fp16 MFMA GEMM, B streamed ==========
// Grid 1024 = 128 row-blocks x 8 code-splits. split = bid&7 -> default XCD
// round-robin pins one split per XCD, so each XCD's 512 KB B-chunk stays
// L2-resident across all 128 row-blocks.
// Block: 4 waves; wave owns 64 rows. A fragments for the FULL K=256 live in
// 128 VGPRs/lane (loaded once, direct global->reg). B streams through a
// 2 x 16 KB double-buffered LDS in 32-code sub-blocks: the next sub-block's
// global_load_lds DMA is issued BEFORE this sub-block's 64 MFMAs and drains
// at the single end-of-iter __syncthreads() -> DMA overlaps compute, one
// barrier per sub-block, no raw-barrier races.
// Per wave per K-step(32): 2 ds_read_b128 (24 cyc) vs 8 MFMA (38.8 cyc) ->
// MFMA-bound (vs 120/77.6 LDS-bound in the old 32x128 both-in-LDS tile).
// Running per-lane top-2 over the 1024-code sweep; one cross-lane butterfly
// merge at the end.
// KEY (fixed from round 2): x rows are RAW (not normalized; argmax is scale-
// invariant and the rescore divides by ||x|| exactly), so |v| <= ||x||*||c||
// <= ~19*19 = 361 < 512 worst-case. q = trunc(clamp(v*4096 + 2^21, 0, 2^22-1))
// is monotone (fp32 rounding is monotone, trunc is monotone), 22 bits; key =
// (q << 10) | (1023 - pos) is 32 bits, resolution 1/4096 = 2.4e-4 (same as
// the proven round-0 scheme). Round-2's v*65536 variant saturated at |v|>=32,
// which ~190 codes/row exceed -> wrong candidates everywhere.
__global__ __launch_bounds__(256, 2) void gemm_kernel(const _Float16* __restrict__ xh,
                                                      const _Float16* __restrict__ ch,
                                                      uint2* __restrict__ ptop) {
    __shared__ _Float16 sB[2][32 * CDIM];          // 2 x 16 KB, XOR-swizzled

    int t = threadIdx.x;
    int w = t >> 6, lane = t & 63;
    int cc2 = lane & 15, qq = lane >> 4;
    int bid = blockIdx.x;
    int split  = bid & 7;
    int rowblk = bid >> 3;
    int rw = rowblk * 256 + w * 64;                // wave row base
    int c0 = split * CPB;                          // code base

    // ---- A fragments: full K in registers (4 mi x 8 ks x f16x8 = 128 VGPR) --
    f16x8 a[4][8];
    {
        const _Float16* ap = xh + (size_t)(rw + cc2) * CDIM + qq * 8;
        #pragma unroll
        for (int mi = 0; mi < 4; ++mi)
            #pragma unroll
            for (int ks = 0; ks < 8; ++ks)
                a[mi][ks] = *(const f16x8*)(ap + (size_t)(mi * 16) * CDIM + ks * 32);
    }

    // ---- staging geometry: pre-swizzled global source, linear LDS dest ------
    // chunk = it*256 + t; LDS slot (code c = chunk>>5, group g = chunk&31)
    // holds global group j = g ^ (c&7). c&7 == (t>>5)&7 for every it, so the
    // per-thread source offset is it-invariant modulo a +8-codes stride.
    const _Float16* sb_src = ch + (size_t)(c0 + (t >> 5)) * CDIM
                                + (((t & 31) ^ ((t >> 5) & 7)) << 3);
    char* dst0 = (char*)&sB[0][0] + (w * 64) * 16;
    char* dst1 = (char*)&sB[1][0] + (w * 64) * 16;

    // prologue: stage sub-block 0 into buffer 0 (A loads drain here too)
    #pragma unroll
    for (int it = 0; it < 4; ++it)
        load16_to_lds(sb_src + (size_t)(it * 8) * CDIM, dst0 + it * 4096);
    __syncthreads();

    uint32_t k1[4][4], k2[4][4];
    #pragma unroll
    for (int mi = 0; mi < 4; ++mi)
        #pragma unroll
        for (int r = 0; r < 4; ++r) { k1[mi][r] = 0u; k2[mi][r] = 0u; }

    #pragma unroll 2
    for (int s = 0; s < NSB; ++s) {
        // issue next sub-block's DMA now; it overlaps this sub-block's MFMAs
        if (s < NSB - 1) {
            const _Float16* src = sb_src + (size_t)((s + 1) * 32) * CDIM;
            char* dst = (s & 1) ? dst0 : dst1;
            #pragma unroll
            for (int it = 0; it < 4; ++it)
                load16_to_lds(src + (size_t)(it * 8) * CDIM, dst + it * 4096);
        }

        const char* bufB = (const char*)&sB[s & 1][0];
        f32x4 acc[2][4];
        f32x4 zero = {0.f, 0.f, 0.f, 0.f};
        #pragma unroll
        for (int ni = 0; ni < 2; ++ni)
            #pragma unroll
            for (int mi = 0; mi < 4; ++mi) acc[ni][mi] = zero;

        #pragma unroll
        for (int ks = 0; ks < 8; ++ks) {
            #pragma unroll
            for (int ni = 0; ni < 2; ++ni) {
                int c = ni * 16 + cc2;
                int g = (ks * 4 + qq) ^ (c & 7);
                f16x8 bf = *(const f16x8*)(bufB + c * 512 + g * 16);
                acc[ni][0] = __builtin_amdgcn_mfma_f32_16x16x32_f16(a[0][ks], bf, acc[ni][0], 0, 0, 0);
                acc[ni][1] = __builtin_amdgcn_mfma_f32_16x16x32_f16(a[1][ks], bf, acc[ni][1], 0, 0, 0);
                acc[ni][2] = __builtin_amdgcn_mfma_f32_16x16x32_f16(a[2][ks], bf, acc[ni][2], 0, 0, 0);
                acc[ni][3] = __builtin_amdgcn_mfma_f32_16x16x32_f16(a[3][ks], bf, acc[ni][3], 0, 0, 0);
            }
        }

        // branch-free insert of 32 fresh keys into per-lane running top-2
        #pragma unroll
        for (int ni = 0; ni < 2; ++ni) {
            uint32_t tag = (uint32_t)(1023 - s * 32 - ni * 16 - cc2);
            #pragma unroll
            for (int mi = 0; mi < 4; ++mi)
                #pragma unroll
                for (int r = 0; r < 4; ++r) {
                    float qf = fmaf(acc[ni][mi][r], 4096.0f, 2097152.0f);
                    qf = fminf(fmaxf(qf, 0.0f), 4194303.0f);
                    uint32_t q = (uint32_t)qf;
                    uint32_t key = (q << 10) | tag;
                    uint32_t K1 = k1[mi][r];
                    uint32_t hi = K1 > key ? K1 : key;
                    uint32_t lo = K1 > key ? key : K1;
                    k1[mi][r] = hi;
                    uint32_t K2 = k2[mi][r];
                    k2[mi][r] = K2 > lo ? K2 : lo;
                }
        }
        __syncthreads();   // next iter's DMA overwrites the buffer just read
    }

    // cross-lane (16-code columns) top-2 merge + write one uint2 per row
    #pragma unroll
    for (int mi = 0; mi < 4; ++mi)
        #pragma unroll
        for (int r = 0; r < 4; ++r) {
            uint32_t K1 = k1[mi][r], K2 = k2[mi][r];
            #pragma unroll
            for (int msk = 1; msk <= 8; msk <<= 1) {
                uint32_t o1 = (uint32_t)__shfl_xor((int)K1, msk);
                uint32_t o2 = (uint32_t)__shfl_xor((int)K2, msk);
                uint32_t hi = K1 > o1 ? K1 : o1;
                uint32_t lo = K1 > o1 ? o1 : K1;
                uint32_t t2 = K2 > o2 ? K2 : o2;
                K1 = hi;
                K2 = lo > t2 ? lo : t2;
            }
            if (cc2 == 0) {
                int row = rw + mi * 16 + qq * 4 + r;
                ptop[(size_t)split * NROWS + row] = make_uint2(K1, K2);
            }
        }
}

// =============== Kernel 3: merge 8 splits -> global top-4 code ids ============
__global__ __launch_bounds__(256) void reduce_kernel(const uint2* __restrict__ ptop,
                                                     int4* __restrict__ cand) {
    int n = blockIdx.x * 256 + threadIdx.x;   // 128 blocks
    u64 k[4] = {0ull, 0ull, 0ull, 0ull};
    #pragma unroll
    for (int sp = 0; sp < SPLITS; ++sp) {
        uint2 e = ptop[(size_t)sp * NROWS + n];
        ins4(((u64)e.x << 3) | (unsigned)sp, k);
        ins4(((u64)e.y << 3) | (unsigned)sp, k);
    }
    int code[4];
    #pragma unroll
    for (int j = 0; j < 4; ++j) {
        int sp       = (int)(k[j] & 7u);
        uint32_t key = (uint32_t)(k[j] >> 3);
        code[j] = sp * CPB + 1023 - (int)(key & 1023u);
    }
    cand[n] = make_int4(code[0], code[1], code[2], code[3]);
}

// =============== Kernel 4: exact fp32 rescore (coalesced) -> winner idx + loss =
// 2048 blocks, 256 threads; 16 lanes per row -> 16 rows per block.
__global__ __launch_bounds__(256) void rescore_kernel(const float* __restrict__ xt,
                                                      const float* __restrict__ cb,
                                                      const int4* __restrict__ cand,
                                                      int* __restrict__ widx,
                                                      float* __restrict__ loss_sum) {
    int t = threadIdx.x, l = t & 63;
    int cl = t & 15;
    int n = blockIdx.x * 16 + (t >> 4);
    int4 cd = cand[n];
    const float* xr = xt + (size_t)n * CDIM + cl * 16;
    const float* r0 = cb + (size_t)cd.x * CDIM + cl * 16;
    const float* r1 = cb + (size_t)cd.y * CDIM + cl * 16;
    const float* r2 = cb + (size_t)cd.z * CDIM + cl * 16;
    const float* r3 = cb + (size_t)cd.w * CDIM + cl * 16;
    float n2 = 0.f, d0 = 0.f, d1 = 0.f, d2 = 0.f, d3 = 0.f;
    #pragma unroll
    for (int chk = 0; chk < 4; ++chk) {
        float4 xv = *(const float4*)(xr + chk * 4);
        float4 a0 = *(const float4*)(r0 + chk * 4);
        float4 a1 = *(const float4*)(r1 + chk * 4);
        float4 a2 = *(const float4*)(r2 + chk * 4);
        float4 a3 = *(const float4*)(r3 + chk * 4);
        float xs[4] = {xv.x, xv.y, xv.z, xv.w};
        float b0[4] = {a0.x, a0.y, a0.z, a0.w};
        float b1[4] = {a1.x, a1.y, a1.z, a1.w};
        float b2[4] = {a2.x, a2.y, a2.z, a2.w};
        float b3[4] = {a3.x, a3.y, a3.z, a3.w};
        #pragma unroll
        for (int j = 0; j < 4; ++j) {
            n2 = fmaf(xs[j], xs[j], n2);
            d0 = fmaf(xs[j], b0[j], d0);
            d1 = fmaf(xs[j], b1[j], d1);
            d2 = fmaf(xs[j], b2[j], d2);
            d3 = fmaf(xs[j], b3[j], d3);
        }
    }
    #pragma unroll
    for (int m = 1; m <= 8; m <<= 1) {
        n2 += __shfl_xor(n2, m);
        d0 += __shfl_xor(d0, m);
        d1 += __shfl_xor(d1, m);
        d2 += __shfl_xor(d2, m);
        d3 += __shfl_xor(d3, m);
    }
    float lp = 0.f;
    if (cl == 0) {
        float bD = d0; int bI = cd.x;
        if (d1 > bD || (d1 == bD && cd.y < bI)) { bD = d1; bI = cd.y; }
        if (d2 > bD || (d2 == bD && cd.z < bI)) { bD = d2; bI = cd.z; }
        if (d3 > bD || (d3 == bD && cd.w < bI)) { bD = d3; bI = cd.w; }
        widx[n] = bI;
        lp = bD / fmaxf(sqrtf(n2), 1e-12f);
    }
    #pragma unroll
    for (int m = 1; m <= 32; m <<= 1) lp += __shfl_xor(lp, m);
    if (l == 0) atomicAdd(loss_sum, lp);
}

// =============== Kernel 5: gather q via LDS transpose + coalesced write + loss =
__global__ __launch_bounds__(256) void writeq_kernel(const float* __restrict__ cb,
                                                     const int* __restrict__ widx,
                                                     const float* __restrict__ loss_sum,
                                                     float* __restrict__ out) {
    __shared__ float rows[64][260];       // pad 260 (16B-aligned rows)
    int bh = blockIdx.x;                  // b*64 + h, 512 blocks
    int b = bh >> 6, h = bh & 63;
    int t = threadIdx.x;
    int rr = t >> 6, cq = t & 63;
    #pragma unroll 4
    for (int i = 0; i < 16; ++i) {
        int wv = i * 4 + rr;
        int id = widx[bh * 64 + wv];
        float4 v = *(const float4*)(cb + (size_t)id * CDIM + cq * 4);
        *(float4*)&rows[wv][cq * 4] = v;
    }
    __syncthreads();
    int wl = t & 63, cg = t >> 6;
    float* ob = out + (size_t)b * CDIM * HWP + h * 64 + wl;
    #pragma unroll 4
    for (int c = cg * 64; c < cg * 64 + 64; ++c)
        ob[(size_t)c * HWP] = rows[wl][c];
    if (bh == 0 && t == 0) {
        float mean = loss_sum[0] / 32768.0f;
        out[8388608] = 0.25f * (1.0f - mean);
        out[8388609] = 1.0f  * (1.0f - mean);
    }
}

extern "C" void kernel_launch(void* const* d_in, const int* in_sizes, int n_in,
                              void* d_out, int out_size, void* d_ws, size_t ws_size,
                              hipStream_t stream) {
    const float* x  = (const float*)d_in[0];   // [8,256,64,64]
    const float* cb = (const float*)d_in[1];   // [8192,256]
    float* out = (float*)d_out;

    char* ws = (char*)d_ws;
    _Float16* xh   = (_Float16*)(ws);                     // 16,777,216 B
    _Float16* ch   = (_Float16*)(ws + 16777216);          //  4,194,304 B
    float*    xt   = (float*)   (ws + 20971520);          // 33,554,432 B
    uint2*    ptop = (uint2*)   (ws + 54525952);          //  2,097,152 B
    int4*     cand = (int4*)    (ws + 71303168);          //    524,288 B
    int*      widx = (int*)     (ws + 71827456);          //    131,072 B
    float*    loss = (float*)   (ws + 71958528);          //          4 B

    hipMemsetAsync(loss, 0, 4, stream);
    split_x_kernel <<<dim3(64, 4, 8), 256, 0, stream>>>(x, xh, xt);
    split_cb_kernel<<<2048,           256, 0, stream>>>(cb, ch);
    gemm_kernel    <<<1024,           256, 0, stream>>>(xh, ch, ptop);
    reduce_kernel  <<<128,            256, 0, stream>>>(ptop, cand);
    rescore_kernel <<<2048,           256, 0, stream>>>(xt, cb, cand, widx, loss);
    writeq_kernel  <<<512,            256, 0, stream>>>(cb, widx, loss, out);
}

// Round 4
// 362.049 us; speedup vs baseline: 1.2099x; 1.0088x over previous
//
#include <hip/hip_runtime.h>
#include <hip/hip_bf16.h>
#include <cstdint>

#define HWP    4096
#define CDIM   256
#define KCODES 8192
#define NROWS  32768
#define SPLITS 8           // code-splits; split = bid & 7 -> one split per XCD
#define CPB    1024        // codes per block = KCODES / SPLITS
#define NSB    32          // sub-blocks of 32 codes per block

typedef _Float16 f16x8 __attribute__((ext_vector_type(8)));
typedef float    f32x4 __attribute__((ext_vector_type(4)));
typedef unsigned long long u64;

// ---- async global->LDS, 16B per lane; LDS dest = wave-uniform base + lane*16 ----
__device__ __forceinline__ void load16_to_lds(const void* g, void* s) {
    __builtin_amdgcn_global_load_lds(
        (const __attribute__((address_space(1))) void*)(uintptr_t)g,
        (__attribute__((address_space(3))) void*)(uintptr_t)s,
        16, 0, 0);
}

// u64 branch-free top-4 insert (for the tiny reduce kernel)
__device__ __forceinline__ void ins4(u64 c, u64 k[4]) {
    u64 a;
    a = k[0] > c ? k[0] : c;  c = k[0] > c ? c : k[0];  k[0] = a;
    a = k[1] > c ? k[1] : c;  c = k[1] > c ? c : k[1];  k[1] = a;
    a = k[2] > c ? k[2] : c;  c = k[2] > c ? c : k[2];  k[2] = a;
    k[3] = k[3] > c ? k[3] : c;
}

// =============== Kernel 1a: transpose x -> xh fp16 [N][C] + xt fp32 [N][C] ====
__global__ __launch_bounds__(256) void split_x_kernel(const float* __restrict__ x,
                                                      _Float16* __restrict__ xh,
                                                      float* __restrict__ xt) {
    __shared__ float tile[64][65];
    int pb = blockIdx.x, cbk = blockIdx.y, b = blockIdx.z;
    int t = threadIdx.x;
    int p0 = pb * 64, c0 = cbk * 64;
    int pl = t & 63, cl = t >> 6;
    const float* src = x + ((size_t)b * CDIM + c0) * HWP + p0;
    #pragma unroll 4
    for (int i = 0; i < 16; ++i) {
        int c = cl * 16 + i;
        tile[c][pl] = src[(size_t)c * HWP + pl];
    }
    __syncthreads();
    int p = t >> 2, cq = (t & 3) * 16;
    size_t n = (size_t)b * HWP + p0 + p;
    alignas(16) _Float16 hbuf[16];
    alignas(16) float    fbuf[16];
    #pragma unroll
    for (int j = 0; j < 16; ++j) {
        float v = tile[cq + j][p];
        fbuf[j] = v;
        hbuf[j] = (_Float16)v;
    }
    *(int4*)(xh + n * CDIM + c0 + cq)     = ((int4*)hbuf)[0];
    *(int4*)(xh + n * CDIM + c0 + cq + 8) = ((int4*)hbuf)[1];
    #pragma unroll
    for (int j = 0; j < 4; ++j)
        *(float4*)(xt + n * CDIM + c0 + cq + j * 4) = ((float4*)fbuf)[j];
}

// =============== Kernel 1b: convert codebook [K][C] -> fp16 ===================
__global__ __launch_bounds__(256) void split_cb_kernel(const float* __restrict__ cb,
                                                       _Float16* __restrict__ ch) {
    int i4 = blockIdx.x * 256 + threadIdx.x;          // 2048 blocks
    float4 v = ((const float4*)cb)[i4];
    alignas(8) _Float16 h[4];
    h[0] = (_Float16)v.x; h[1] = (_Float16)v.y;
    h[2] = (_Float16)v.z; h[3] = (_Float16)v.w;
    *(uint2*)(ch + (size_t)i4 * 4) = *(uint2*)h;
}

// =============== Kernel 2: A-in-registers fp16 MFMA GEMM, B streamed ==========
// Grid 1024 = 128 row-blocks x 8 code-splits; split = bid&7 -> one per XCD.
// Wave owns 64 rows; A for full K=256 in 128 VGPRs. B streams via 2x16 KB
// double-buffered LDS, 32 codes/sub-block, DMA issued before compute, one
// __syncthreads per iter (drains the DMA).
//
// ROUND-4 CHANGES (counter-driven):
// 1) LDS slot permutation: slot sigma = (cc2&7)*4 + (cc2>>3)*2 + ni (was
//    ni*16+cc2). Same-bank read pairs (cc2,cc2+8) now sit 2 rows = 1024 B
//    apart -- the round-0 geometry that measured 0 bank conflicts -- vs
//    round-3's 4096 B gap that measured 8.4M (= 4/ds_read_b128).
//    Staging pre-permutes the global source (both-sides-or-neither);
//    read-side XOR spread h = (ks*4+qq) ^ (cc2&7) unchanged.
// 2) Float-bits key (VALUBusy 49% was top pipe): |v| <= ||x||*||c|| < 512,
//    so v+4608 in (4096,5120) -- one binade, top-2 mantissa bits 00 ->
//    key = (bits(v+4608)<<10) | tag is lossless-monotone. 2 VALU/keygen
//    (add + lshl_or) vs 8 (fmaf/min/max/cvt/or). Pair-merge insert keeps
//    top-2 in 6 ops per 2 keys. Resolution 4.9e-4; exact fp32 top-4
//    rescore downstream absorbs quantization. tag = 1023 - pos with
//    pos = s*32 + ni*16 + (cc2>>3)*8 + (cc2&7); reduce_kernel unchanged.
__global__ __launch_bounds__(256, 2) void gemm_kernel(const _Float16* __restrict__ xh,
                                                      const _Float16* __restrict__ ch,
                                                      uint2* __restrict__ ptop) {
    __shared__ _Float16 sB[2][32 * CDIM];          // 2 x 16 KB

    int t = threadIdx.x;
    int w = t >> 6, lane = t & 63;
    int cc2 = lane & 15, qq = lane >> 4;
    int bid = blockIdx.x;
    int split  = bid & 7;
    int rowblk = bid >> 3;
    int rw = rowblk * 256 + w * 64;                // wave row base
    int c0 = split * CPB;                          // code base

    // ---- A fragments: full K in registers (4 mi x 8 ks x f16x8 = 128 VGPR) --
    f16x8 a[4][8];
    {
        const _Float16* ap = xh + (size_t)(rw + cc2) * CDIM + qq * 8;
        #pragma unroll
        for (int mi = 0; mi < 4; ++mi)
            #pragma unroll
            for (int ks = 0; ks < 8; ++ks)
                a[mi][ks] = *(const f16x8*)(ap + (size_t)(mi * 16) * CDIM + ks * 32);
    }

    // ---- staging geometry (slot-permuted, pre-swizzled global source) -------
    // LDS linear chunk = it*256 + t -> slot sigma = chunk>>5, chunk-off h = t&31.
    // Slot sigma holds code w(sigma) = ((sig&1)<<4)|(((sig>>1)&1)<<3)|(sig>>2),
    // k-chunk j = h ^ (sigma>>2). With sigma = it*8 + (t>>5):
    //   sigma>>2 = it*2 + (t>>7)... = it*2 + ((t>>5)>>2), all per-it constants.
    const int u_ = t >> 5;                         // 0..7
    const _Float16* sbs[4];
    #pragma unroll
    for (int it = 0; it < 4; ++it) {
        int rot   = it * 2 + (u_ >> 2);            // sigma>>2  (0..7)
        int wcode = ((u_ & 1) << 4) | (((u_ >> 1) & 1) << 3) | rot;
        int j     = (t & 31) ^ rot;
        sbs[it] = ch + (size_t)(c0 + wcode) * CDIM + j * 8;
    }
    char* dst0 = (char*)&sB[0][0] + (w * 64) * 16;
    char* dst1 = (char*)&sB[1][0] + (w * 64) * 16;

    // prologue: stage sub-block 0 into buffer 0 (A loads drain here too)
    #pragma unroll
    for (int it = 0; it < 4; ++it)
        load16_to_lds(sbs[it], dst0 + it * 4096);
    __syncthreads();

    // read-side lane constants
    const int sig2 = (cc2 & 7) * 4 + ((cc2 >> 3) << 1);   // sigma minus ni
    const int gx   = cc2 & 7;                             // xor spread
    const uint32_t tbase = (uint32_t)(1023 - ((cc2 >> 3) * 8 + (cc2 & 7)));

    uint32_t k1[4][4], k2[4][4];
    #pragma unroll
    for (int mi = 0; mi < 4; ++mi)
        #pragma unroll
        for (int r = 0; r < 4; ++r) { k1[mi][r] = 0u; k2[mi][r] = 0u; }

    #pragma unroll 2
    for (int s = 0; s < NSB; ++s) {
        // issue next sub-block's DMA now; it overlaps this sub-block's MFMAs
        if (s < NSB - 1) {
            size_t soff = (size_t)(s + 1) * 32 * CDIM;
            char* dst = (s & 1) ? dst0 : dst1;
            #pragma unroll
            for (int it = 0; it < 4; ++it)
                load16_to_lds(sbs[it] + soff, dst + it * 4096);
        }

        const char* bufB = (const char*)&sB[s & 1][0];
        f32x4 acc[2][4];
        f32x4 zero = {0.f, 0.f, 0.f, 0.f};
        #pragma unroll
        for (int ni = 0; ni < 2; ++ni)
            #pragma unroll
            for (int mi = 0; mi < 4; ++mi) acc[ni][mi] = zero;

        #pragma unroll
        for (int ks = 0; ks < 8; ++ks) {
            int g = (ks * 4 + qq) ^ gx;
            const char* bb = bufB + sig2 * 512 + g * 16;
            f16x8 bf0 = *(const f16x8*)(bb);
            f16x8 bf1 = *(const f16x8*)(bb + 512);
            acc[0][0] = __builtin_amdgcn_mfma_f32_16x16x32_f16(a[0][ks], bf0, acc[0][0], 0, 0, 0);
            acc[0][1] = __builtin_amdgcn_mfma_f32_16x16x32_f16(a[1][ks], bf0, acc[0][1], 0, 0, 0);
            acc[0][2] = __builtin_amdgcn_mfma_f32_16x16x32_f16(a[2][ks], bf0, acc[0][2], 0, 0, 0);
            acc[0][3] = __builtin_amdgcn_mfma_f32_16x16x32_f16(a[3][ks], bf0, acc[0][3], 0, 0, 0);
            acc[1][0] = __builtin_amdgcn_mfma_f32_16x16x32_f16(a[0][ks], bf1, acc[1][0], 0, 0, 0);
            acc[1][1] = __builtin_amdgcn_mfma_f32_16x16x32_f16(a[1][ks], bf1, acc[1][1], 0, 0, 0);
            acc[1][2] = __builtin_amdgcn_mfma_f32_16x16x32_f16(a[2][ks], bf1, acc[1][2], 0, 0, 0);
            acc[1][3] = __builtin_amdgcn_mfma_f32_16x16x32_f16(a[3][ks], bf1, acc[1][3], 0, 0, 0);
        }

        // float-bits keys, pair-merge top-2 insert (branch-free)
        uint32_t tag0 = tbase - (uint32_t)(s * 32);
        #pragma unroll
        for (int mi = 0; mi < 4; ++mi)
            #pragma unroll
            for (int r = 0; r < 4; ++r) {
                uint32_t u0 = __float_as_uint(acc[0][mi][r] + 4608.0f);
                uint32_t u1 = __float_as_uint(acc[1][mi][r] + 4608.0f);
                uint32_t key0 = (u0 << 10) | tag0;
                uint32_t key1 = (u1 << 10) | (tag0 - 16u);
                uint32_t p1 = key0 > key1 ? key0 : key1;
                uint32_t p2 = key0 > key1 ? key1 : key0;
                uint32_t K1 = k1[mi][r];
                uint32_t n1 = K1 > p1 ? K1 : p1;
                uint32_t tt = K1 > p1 ? p1 : K1;
                uint32_t m2 = k2[mi][r] > p2 ? k2[mi][r] : p2;
                k2[mi][r] = m2 > tt ? m2 : tt;
                k1[mi][r] = n1;
            }
        __syncthreads();   // next iter's DMA overwrites the buffer just read
    }

    // cross-lane (16-code columns) top-2 merge + write one uint2 per row
    #pragma unroll
    for (int mi = 0; mi < 4; ++mi)
        #pragma unroll
        for (int r = 0; r < 4; ++r) {
            uint32_t K1 = k1[mi][r], K2 = k2[mi][r];
            #pragma unroll
            for (int msk = 1; msk <= 8; msk <<= 1) {
                uint32_t o1 = (uint32_t)__shfl_xor((int)K1, msk);
                uint32_t o2 = (uint32_t)__shfl_xor((int)K2, msk);
                uint32_t hi = K1 > o1 ? K1 : o1;
                uint32_t lo = K1 > o1 ? o1 : K1;
                uint32_t t2 = K2 > o2 ? K2 : o2;
                K1 = hi;
                K2 = lo > t2 ? lo : t2;
            }
            if (cc2 == 0) {
                int row = rw + mi * 16 + qq * 4 + r;
                ptop[(size_t)split * NROWS + row] = make_uint2(K1, K2);
            }
        }
}

// =============== Kernel 3: merge 8 splits -> global top-4 code ids ============
__global__ __launch_bounds__(256) void reduce_kernel(const uint2* __restrict__ ptop,
                                                     int4* __restrict__ cand) {
    int n = blockIdx.x * 256 + threadIdx.x;   // 128 blocks
    u64 k[4] = {0ull, 0ull, 0ull, 0ull};
    #pragma unroll
    for (int sp = 0; sp < SPLITS; ++sp) {
        uint2 e = ptop[(size_t)sp * NROWS + n];
        ins4(((u64)e.x << 3) | (unsigned)sp, k);
        ins4(((u64)e.y << 3) | (unsigned)sp, k);
    }
    int code[4];
    #pragma unroll
    for (int j = 0; j < 4; ++j) {
        int sp       = (int)(k[j] & 7u);
        uint32_t key = (uint32_t)(k[j] >> 3);
        code[j] = sp * CPB + 1023 - (int)(key & 1023u);
    }
    cand[n] = make_int4(code[0], code[1], code[2], code[3]);
}

// =============== Kernel 4: exact fp32 rescore (coalesced) -> winner idx + loss =
// 2048 blocks, 256 threads; 16 lanes per row -> 16 rows per block.
__global__ __launch_bounds__(256) void rescore_kernel(const float* __restrict__ xt,
                                                      const float* __restrict__ cb,
                                                      const int4* __restrict__ cand,
                                                      int* __restrict__ widx,
                                                      float* __restrict__ loss_sum) {
    int t = threadIdx.x, l = t & 63;
    int cl = t & 15;
    int n = blockIdx.x * 16 + (t >> 4);
    int4 cd = cand[n];
    const float* xr = xt + (size_t)n * CDIM + cl * 16;
    const float* r0 = cb + (size_t)cd.x * CDIM + cl * 16;
    const float* r1 = cb + (size_t)cd.y * CDIM + cl * 16;
    const float* r2 = cb + (size_t)cd.z * CDIM + cl * 16;
    const float* r3 = cb + (size_t)cd.w * CDIM + cl * 16;
    float n2 = 0.f, d0 = 0.f, d1 = 0.f, d2 = 0.f, d3 = 0.f;
    #pragma unroll
    for (int chk = 0; chk < 4; ++chk) {
        float4 xv = *(const float4*)(xr + chk * 4);
        float4 a0 = *(const float4*)(r0 + chk * 4);
        float4 a1 = *(const float4*)(r1 + chk * 4);
        float4 a2 = *(const float4*)(r2 + chk * 4);
        float4 a3 = *(const float4*)(r3 + chk * 4);
        float xs[4] = {xv.x, xv.y, xv.z, xv.w};
        float b0[4] = {a0.x, a0.y, a0.z, a0.w};
        float b1[4] = {a1.x, a1.y, a1.z, a1.w};
        float b2[4] = {a2.x, a2.y, a2.z, a2.w};
        float b3[4] = {a3.x, a3.y, a3.z, a3.w};
        #pragma unroll
        for (int j = 0; j < 4; ++j) {
            n2 = fmaf(xs[j], xs[j], n2);
            d0 = fmaf(xs[j], b0[j], d0);
            d1 = fmaf(xs[j], b1[j], d1);
            d2 = fmaf(xs[j], b2[j], d2);
            d3 = fmaf(xs[j], b3[j], d3);
        }
    }
    #pragma unroll
    for (int m = 1; m <= 8; m <<= 1) {
        n2 += __shfl_xor(n2, m);
        d0 += __shfl_xor(d0, m);
        d1 += __shfl_xor(d1, m);
        d2 += __shfl_xor(d2, m);
        d3 += __shfl_xor(d3, m);
    }
    float lp = 0.f;
    if (cl == 0) {
        float bD = d0; int bI = cd.x;
        if (d1 > bD || (d1 == bD && cd.y < bI)) { bD = d1; bI = cd.y; }
        if (d2 > bD || (d2 == bD && cd.z < bI)) { bD = d2; bI = cd.z; }
        if (d3 > bD || (d3 == bD && cd.w < bI)) { bD = d3; bI = cd.w; }
        widx[n] = bI;
        lp = bD / fmaxf(sqrtf(n2), 1e-12f);
    }
    #pragma unroll
    for (int m = 1; m <= 32; m <<= 1) lp += __shfl_xor(lp, m);
    if (l == 0) atomicAdd(loss_sum, lp);
}

// =============== Kernel 5: gather q via LDS transpose + coalesced write + loss =
__global__ __launch_bounds__(256) void writeq_kernel(const float* __restrict__ cb,
                                                     const int* __restrict__ widx,
                                                     const float* __restrict__ loss_sum,
                                                     float* __restrict__ out) {
    __shared__ float rows[64][260];       // pad 260 (16B-aligned rows)
    int bh = blockIdx.x;                  // b*64 + h, 512 blocks
    int b = bh >> 6, h = bh & 63;
    int t = threadIdx.x;
    int rr = t >> 6, cq = t & 63;
    #pragma unroll 4
    for (int i = 0; i < 16; ++i) {
        int wv = i * 4 + rr;
        int id = widx[bh * 64 + wv];
        float4 v = *(const float4*)(cb + (size_t)id * CDIM + cq * 4);
        *(float4*)&rows[wv][cq * 4] = v;
    }
    __syncthreads();
    int wl = t & 63, cg = t >> 6;
    float* ob = out + (size_t)b * CDIM * HWP + h * 64 + wl;
    #pragma unroll 4
    for (int c = cg * 64; c < cg * 64 + 64; ++c)
        ob[(size_t)c * HWP] = rows[wl][c];
    if (bh == 0 && t == 0) {
        float mean = loss_sum[0] / 32768.0f;
        out[8388608] = 0.25f * (1.0f - mean);
        out[8388609] = 1.0f  * (1.0f - mean);
    }
}

extern "C" void kernel_launch(void* const* d_in, const int* in_sizes, int n_in,
                              void* d_out, int out_size, void* d_ws, size_t ws_size,
                              hipStream_t stream) {
    const float* x  = (const float*)d_in[0];   // [8,256,64,64]
    const float* cb = (const float*)d_in[1];   // [8192,256]
    float* out = (float*)d_out;

    char* ws = (char*)d_ws;
    _Float16* xh   = (_Float16*)(ws);                     // 16,777,216 B
    _Float16* ch   = (_Float16*)(ws + 16777216);          //  4,194,304 B
    float*    xt   = (float*)   (ws + 20971520);          // 33,554,432 B
    uint2*    ptop = (uint2*)   (ws + 54525952);          //  2,097,152 B
    int4*     cand = (int4*)    (ws + 71303168);          //    524,288 B
    int*      widx = (int*)     (ws + 71827456);          //    131,072 B
    float*    loss = (float*)   (ws + 71958528);          //          4 B

    hipMemsetAsync(loss, 0, 4, stream);
    split_x_kernel <<<dim3(64, 4, 8), 256, 0, stream>>>(x, xh, xt);
    split_cb_kernel<<<2048,           256, 0, stream>>>(cb, ch);
    gemm_kernel    <<<1024,           256, 0, stream>>>(xh, ch, ptop);
    reduce_kernel  <<<128,            256, 0, stream>>>(ptop, cand);
    rescore_kernel <<<2048,           256, 0, stream>>>(xt, cb, cand, widx, loss);
    writeq_kernel  <<<512,            256, 0, stream>>>(cb, widx, loss, out);
}

// Round 5
// 313.290 us; speedup vs baseline: 1.3983x; 1.1556x over previous
//
#include <hip/hip_runtime.h>
#include <hip/hip_bf16.h>
#include <cstdint>

#define HWP    4096
#define CDIM   256
#define KCODES 8192
#define NROWS  32768
#define SPLITS 8           // code-splits; split = bid & 7 -> one split per XCD
#define CPB    1024        // codes per block = KCODES / SPLITS
#define NSB    32          // sub-blocks of 32 codes per block

typedef _Float16 f16x8 __attribute__((ext_vector_type(8)));
typedef float    f32x4 __attribute__((ext_vector_type(4)));
typedef unsigned long long u64;

// ---- async global->LDS, 16B per lane; LDS dest = wave-uniform base + lane*16 ----
__device__ __forceinline__ void load16_to_lds(const void* g, void* s) {
    __builtin_amdgcn_global_load_lds(
        (const __attribute__((address_space(1))) void*)(uintptr_t)g,
        (__attribute__((address_space(3))) void*)(uintptr_t)s,
        16, 0, 0);
}

// u64 branch-free top-4 insert
__device__ __forceinline__ void ins4(u64 c, u64 k[4]) {
    u64 a;
    a = k[0] > c ? k[0] : c;  c = k[0] > c ? c : k[0];  k[0] = a;
    a = k[1] > c ? k[1] : c;  c = k[1] > c ? c : k[1];  k[1] = a;
    a = k[2] > c ? k[2] : c;  c = k[2] > c ? c : k[2];  k[2] = a;
    k[3] = k[3] > c ? k[3] : c;
}

// =============== Kernel 1a: transpose x -> xh fp16 [N][C] + xt fp32 [N][C] ====
__global__ __launch_bounds__(256) void split_x_kernel(const float* __restrict__ x,
                                                      _Float16* __restrict__ xh,
                                                      float* __restrict__ xt) {
    __shared__ float tile[64][65];
    int pb = blockIdx.x, cbk = blockIdx.y, b = blockIdx.z;
    int t = threadIdx.x;
    int p0 = pb * 64, c0 = cbk * 64;
    int pl = t & 63, cl = t >> 6;
    const float* src = x + ((size_t)b * CDIM + c0) * HWP + p0;
    #pragma unroll 4
    for (int i = 0; i < 16; ++i) {
        int c = cl * 16 + i;
        tile[c][pl] = src[(size_t)c * HWP + pl];
    }
    __syncthreads();
    int p = t >> 2, cq = (t & 3) * 16;
    size_t n = (size_t)b * HWP + p0 + p;
    alignas(16) _Float16 hbuf[16];
    alignas(16) float    fbuf[16];
    #pragma unroll
    for (int j = 0; j < 16; ++j) {
        float v = tile[cq + j][p];
        fbuf[j] = v;
        hbuf[j] = (_Float16)v;
    }
    *(int4*)(xh + n * CDIM + c0 + cq)     = ((int4*)hbuf)[0];
    *(int4*)(xh + n * CDIM + c0 + cq + 8) = ((int4*)hbuf)[1];
    #pragma unroll
    for (int j = 0; j < 4; ++j)
        *(float4*)(xt + n * CDIM + c0 + cq + j * 4) = ((float4*)fbuf)[j];
}

// =============== Kernel 1b: convert codebook [K][C] -> fp16 ===================
__global__ __launch_bounds__(256) void split_cb_kernel(const float* __restrict__ cb,
                                                       _Float16* __restrict__ ch) {
    int i4 = blockIdx.x * 256 + threadIdx.x;          // 2048 blocks
    float4 v = ((const float4*)cb)[i4];
    alignas(8) _Float16 h[4];
    h[0] = (_Float16)v.x; h[1] = (_Float16)v.y;
    h[2] = (_Float16)v.z; h[3] = (_Float16)v.w;
    *(uint2*)(ch + (size_t)i4 * 4) = *(uint2*)h;
}

// =============== Kernel 2: A-in-registers fp16 MFMA GEMM, B streamed ==========
// ROUND-5 CHANGE: 4-buffer LDS ring (4 x 16 KB), DMA issued 2 tiles ahead,
// __syncthreads only after odd sub-blocks -> 16 barriers instead of 32.
// Race proof: read of buf[s&3] needs DMA(s) (issued s-2) drained -- the
// barrier ending s-1 or s-2 (one is odd) does it. DMA(s+2) overwrites the
// buffer read at s-2; the same barrier separates those reads from the issue.
// Waves never write LDS (only DMA does), so wave skew within a barrier pair
// is harmless. Keys/fragments/swizzle identical to round 4 (verified).
__global__ __launch_bounds__(256, 2) void gemm_kernel(const _Float16* __restrict__ xh,
                                                      const _Float16* __restrict__ ch,
                                                      uint2* __restrict__ ptop) {
    __shared__ _Float16 sB[4][32 * CDIM];          // 4 x 16 KB ring

    int t = threadIdx.x;
    int w = t >> 6, lane = t & 63;
    int cc2 = lane & 15, qq = lane >> 4;
    int bid = blockIdx.x;
    int split  = bid & 7;
    int rowblk = bid >> 3;
    int rw = rowblk * 256 + w * 64;                // wave row base
    int c0 = split * CPB;                          // code base

    // ---- A fragments: full K in registers (4 mi x 8 ks x f16x8) -------------
    f16x8 a[4][8];
    {
        const _Float16* ap = xh + (size_t)(rw + cc2) * CDIM + qq * 8;
        #pragma unroll
        for (int mi = 0; mi < 4; ++mi)
            #pragma unroll
            for (int ks = 0; ks < 8; ++ks)
                a[mi][ks] = *(const f16x8*)(ap + (size_t)(mi * 16) * CDIM + ks * 32);
    }

    // ---- staging geometry (slot-permuted, pre-swizzled global source) -------
    const int u_ = t >> 5;                         // 0..7
    const _Float16* sbs[4];
    #pragma unroll
    for (int it = 0; it < 4; ++it) {
        int rot   = it * 2 + (u_ >> 2);            // sigma>>2  (0..7)
        int wcode = ((u_ & 1) << 4) | (((u_ >> 1) & 1) << 3) | rot;
        int j     = (t & 31) ^ rot;
        sbs[it] = ch + (size_t)(c0 + wcode) * CDIM + j * 8;
    }
    char* dstw = (char*)&sB[0][0] + (w * 64) * 16;  // wave region within a buffer

    // prologue: DMA tiles 0,1 -> bufs 0,1
    #pragma unroll
    for (int it = 0; it < 4; ++it) {
        load16_to_lds(sbs[it],                        dstw + it * 4096);
        load16_to_lds(sbs[it] + (size_t)(32 * CDIM),  dstw + 16384 + it * 4096);
    }
    __syncthreads();

    // read-side lane constants
    const int sig2 = (cc2 & 7) * 4 + ((cc2 >> 3) << 1);   // sigma minus ni
    const int gx   = cc2 & 7;                             // xor spread
    const uint32_t tbase = (uint32_t)(1023 - ((cc2 >> 3) * 8 + (cc2 & 7)));

    uint32_t k1[4][4], k2[4][4];
    #pragma unroll
    for (int mi = 0; mi < 4; ++mi)
        #pragma unroll
        for (int r = 0; r < 4; ++r) { k1[mi][r] = 0u; k2[mi][r] = 0u; }

    #pragma unroll 2
    for (int s = 0; s < NSB; ++s) {
        // issue DMA for tile s+2 into ring slot (s+2)&3 (overlaps 2 compute iters)
        if (s < NSB - 2) {
            size_t soff = (size_t)(s + 2) * (32 * CDIM);
            char* dst = dstw + ((s + 2) & 3) * 16384;
            #pragma unroll
            for (int it = 0; it < 4; ++it)
                load16_to_lds(sbs[it] + soff, dst + it * 4096);
        }

        const char* bufB = (const char*)&sB[0][0] + (s & 3) * 16384;
        f32x4 acc[2][4];
        f32x4 zero = {0.f, 0.f, 0.f, 0.f};
        #pragma unroll
        for (int ni = 0; ni < 2; ++ni)
            #pragma unroll
            for (int mi = 0; mi < 4; ++mi) acc[ni][mi] = zero;

        #pragma unroll
        for (int ks = 0; ks < 8; ++ks) {
            int g = (ks * 4 + qq) ^ gx;
            const char* bb = bufB + sig2 * 512 + g * 16;
            f16x8 bf0 = *(const f16x8*)(bb);
            f16x8 bf1 = *(const f16x8*)(bb + 512);
            acc[0][0] = __builtin_amdgcn_mfma_f32_16x16x32_f16(a[0][ks], bf0, acc[0][0], 0, 0, 0);
            acc[0][1] = __builtin_amdgcn_mfma_f32_16x16x32_f16(a[1][ks], bf0, acc[0][1], 0, 0, 0);
            acc[0][2] = __builtin_amdgcn_mfma_f32_16x16x32_f16(a[2][ks], bf0, acc[0][2], 0, 0, 0);
            acc[0][3] = __builtin_amdgcn_mfma_f32_16x16x32_f16(a[3][ks], bf0, acc[0][3], 0, 0, 0);
            acc[1][0] = __builtin_amdgcn_mfma_f32_16x16x32_f16(a[0][ks], bf1, acc[1][0], 0, 0, 0);
            acc[1][1] = __builtin_amdgcn_mfma_f32_16x16x32_f16(a[1][ks], bf1, acc[1][1], 0, 0, 0);
            acc[1][2] = __builtin_amdgcn_mfma_f32_16x16x32_f16(a[2][ks], bf1, acc[1][2], 0, 0, 0);
            acc[1][3] = __builtin_amdgcn_mfma_f32_16x16x32_f16(a[3][ks], bf1, acc[1][3], 0, 0, 0);
        }

        // float-bits keys, pair-merge top-2 insert (branch-free)
        uint32_t tag0 = tbase - (uint32_t)(s * 32);
        #pragma unroll
        for (int mi = 0; mi < 4; ++mi)
            #pragma unroll
            for (int r = 0; r < 4; ++r) {
                uint32_t u0 = __float_as_uint(acc[0][mi][r] + 4608.0f);
                uint32_t u1 = __float_as_uint(acc[1][mi][r] + 4608.0f);
                uint32_t key0 = (u0 << 10) | tag0;
                uint32_t key1 = (u1 << 10) | (tag0 - 16u);
                uint32_t p1 = key0 > key1 ? key0 : key1;
                uint32_t p2 = key0 > key1 ? key1 : key0;
                uint32_t K1 = k1[mi][r];
                uint32_t n1 = K1 > p1 ? K1 : p1;
                uint32_t tt = K1 > p1 ? p1 : K1;
                uint32_t m2 = k2[mi][r] > p2 ? k2[mi][r] : p2;
                k2[mi][r] = m2 > tt ? m2 : tt;
                k1[mi][r] = n1;
            }

        if ((s & 1) && s < NSB - 1) __syncthreads();   // one barrier per 2 tiles
    }

    // cross-lane (16-code columns) top-2 merge + write one uint2 per row
    #pragma unroll
    for (int mi = 0; mi < 4; ++mi)
        #pragma unroll
        for (int r = 0; r < 4; ++r) {
            uint32_t K1 = k1[mi][r], K2 = k2[mi][r];
            #pragma unroll
            for (int msk = 1; msk <= 8; msk <<= 1) {
                uint32_t o1 = (uint32_t)__shfl_xor((int)K1, msk);
                uint32_t o2 = (uint32_t)__shfl_xor((int)K2, msk);
                uint32_t hi = K1 > o1 ? K1 : o1;
                uint32_t lo = K1 > o1 ? o1 : K1;
                uint32_t t2 = K2 > o2 ? K2 : o2;
                K1 = hi;
                K2 = lo > t2 ? lo : t2;
            }
            if (cc2 == 0) {
                int row = rw + mi * 16 + qq * 4 + r;
                ptop[(size_t)split * NROWS + row] = make_uint2(K1, K2);
            }
        }
}

// =============== Kernel 3: fused finalize = reduce + rescore + writeq =========
// 512 blocks (one per (b,h)), 256 threads. Phase 1: per-row top-4 candidates
// from ptop (LDS). Phase 2: exact fp32 rescore of 64 rows x 4 cands (4 chunks
// of 16 rows, 16 lanes/row) -> winner in LDS + loss atomicAdd. Phase 3: gather
// q rows via LDS transpose, coalesced write. Loss scalars written by the LAST
// block to finish (device-scope atomic counter in ws).
__global__ __launch_bounds__(256) void finalize_kernel(const uint2* __restrict__ ptop,
                                                       const float* __restrict__ xt,
                                                       const float* __restrict__ cb,
                                                       float* __restrict__ loss_sum,
                                                       unsigned* __restrict__ counter,
                                                       float* __restrict__ out) {
    __shared__ int4  scand[64];
    __shared__ int   swin[64];
    __shared__ float rows[64][260];       // pad 260 (16B-aligned rows)

    int bh = blockIdx.x;                  // b*64 + h
    int b = bh >> 6, h = bh & 63;
    int t = threadIdx.x;

    // ---- phase 1: per-row top-4 over 8 splits ----
    if (t < 64) {
        int n = bh * 64 + t;
        u64 k[4] = {0ull, 0ull, 0ull, 0ull};
        #pragma unroll
        for (int sp = 0; sp < SPLITS; ++sp) {
            uint2 e = ptop[(size_t)sp * NROWS + n];
            ins4(((u64)e.x << 3) | (unsigned)sp, k);
            ins4(((u64)e.y << 3) | (unsigned)sp, k);
        }
        int4 c4;
        int cc[4];
        #pragma unroll
        for (int j = 0; j < 4; ++j) {
            int sp       = (int)(k[j] & 7u);
            uint32_t key = (uint32_t)(k[j] >> 3);
            cc[j] = sp * CPB + 1023 - (int)(key & 1023u);
        }
        c4.x = cc[0]; c4.y = cc[1]; c4.z = cc[2]; c4.w = cc[3];
        scand[t] = c4;
    }
    __syncthreads();

    // ---- phase 2: exact rescore, 4 chunks of 16 rows ----
    int l = t & 63;
    int cl = t & 15;
    float lpacc = 0.f;
    for (int chunk = 0; chunk < 4; ++chunk) {
        int rloc = chunk * 16 + (t >> 4);
        int n = bh * 64 + rloc;
        int4 cd = scand[rloc];
        const float* xr = xt + (size_t)n * CDIM + cl * 16;
        const float* r0 = cb + (size_t)cd.x * CDIM + cl * 16;
        const float* r1 = cb + (size_t)cd.y * CDIM + cl * 16;
        const float* r2 = cb + (size_t)cd.z * CDIM + cl * 16;
        const float* r3 = cb + (size_t)cd.w * CDIM + cl * 16;
        float n2 = 0.f, d0 = 0.f, d1 = 0.f, d2 = 0.f, d3 = 0.f;
        #pragma unroll
        for (int chk = 0; chk < 4; ++chk) {
            float4 xv = *(const float4*)(xr + chk * 4);
            float4 a0 = *(const float4*)(r0 + chk * 4);
            float4 a1 = *(const float4*)(r1 + chk * 4);
            float4 a2 = *(const float4*)(r2 + chk * 4);
            float4 a3 = *(const float4*)(r3 + chk * 4);
            float xs[4] = {xv.x, xv.y, xv.z, xv.w};
            float b0[4] = {a0.x, a0.y, a0.z, a0.w};
            float b1[4] = {a1.x, a1.y, a1.z, a1.w};
            float b2[4] = {a2.x, a2.y, a2.z, a2.w};
            float b3[4] = {a3.x, a3.y, a3.z, a3.w};
            #pragma unroll
            for (int j = 0; j < 4; ++j) {
                n2 = fmaf(xs[j], xs[j], n2);
                d0 = fmaf(xs[j], b0[j], d0);
                d1 = fmaf(xs[j], b1[j], d1);
                d2 = fmaf(xs[j], b2[j], d2);
                d3 = fmaf(xs[j], b3[j], d3);
            }
        }
        #pragma unroll
        for (int m = 1; m <= 8; m <<= 1) {
            n2 += __shfl_xor(n2, m);
            d0 += __shfl_xor(d0, m);
            d1 += __shfl_xor(d1, m);
            d2 += __shfl_xor(d2, m);
            d3 += __shfl_xor(d3, m);
        }
        if (cl == 0) {
            float bD = d0; int bI = cd.x;
            if (d1 > bD || (d1 == bD && cd.y < bI)) { bD = d1; bI = cd.y; }
            if (d2 > bD || (d2 == bD && cd.z < bI)) { bD = d2; bI = cd.z; }
            if (d3 > bD || (d3 == bD && cd.w < bI)) { bD = d3; bI = cd.w; }
            swin[rloc] = bI;
            lpacc += bD / fmaxf(sqrtf(n2), 1e-12f);
        }
    }
    #pragma unroll
    for (int m = 1; m <= 32; m <<= 1) lpacc += __shfl_xor(lpacc, m);
    if (l == 0) atomicAdd(loss_sum, lpacc);
    __syncthreads();

    // ---- phase 3: gather q via LDS transpose + coalesced write ----
    int rr = t >> 6, cq = t & 63;
    #pragma unroll 4
    for (int i = 0; i < 16; ++i) {
        int wv = i * 4 + rr;
        int id = swin[wv];
        float4 v = *(const float4*)(cb + (size_t)id * CDIM + cq * 4);
        *(float4*)&rows[wv][cq * 4] = v;
    }
    __syncthreads();
    int wl = t & 63, cg = t >> 6;
    float* ob = out + (size_t)b * CDIM * HWP + h * 64 + wl;
    #pragma unroll 4
    for (int c = cg * 64; c < cg * 64 + 64; ++c)
        ob[(size_t)c * HWP] = rows[wl][c];

    // ---- last block writes the two loss scalars ----
    __syncthreads();
    if (t == 0) {
        __threadfence();
        unsigned prev = atomicAdd(counter, 1u);
        if (prev == 511u) {
            float total = atomicAdd(loss_sum, 0.0f);   // coherent read
            float mean = total / 32768.0f;
            out[8388608] = 0.25f * (1.0f - mean);
            out[8388609] = 1.0f  * (1.0f - mean);
        }
    }
}

extern "C" void kernel_launch(void* const* d_in, const int* in_sizes, int n_in,
                              void* d_out, int out_size, void* d_ws, size_t ws_size,
                              hipStream_t stream) {
    const float* x  = (const float*)d_in[0];   // [8,256,64,64]
    const float* cb = (const float*)d_in[1];   // [8192,256]
    float* out = (float*)d_out;

    char* ws = (char*)d_ws;
    _Float16* xh   = (_Float16*)(ws);                     // 16,777,216 B
    _Float16* ch   = (_Float16*)(ws + 16777216);          //  4,194,304 B
    float*    xt   = (float*)   (ws + 20971520);          // 33,554,432 B
    uint2*    ptop = (uint2*)   (ws + 54525952);          //  2,097,152 B
    float*    loss = (float*)   (ws + 71958528);          //          4 B
    unsigned* cnt  = (unsigned*)(ws + 71958532);          //          4 B

    hipMemsetAsync(loss, 0, 8, stream);                   // loss + counter
    split_x_kernel <<<dim3(64, 4, 8), 256, 0, stream>>>(x, xh, xt);
    split_cb_kernel<<<2048,           256, 0, stream>>>(cb, ch);
    gemm_kernel    <<<1024,           256, 0, stream>>>(xh, ch, ptop);
    finalize_kernel<<<512,            256, 0, stream>>>(ptop, xt, cb, loss, cnt, out);
}

// Round 8
// 279.959 us; speedup vs baseline: 1.5647x; 1.1191x over previous
//
#include <hip/hip_runtime.h>
#include <hip/hip_bf16.h>
#include <cstdint>

#define HWP    4096
#define CDIM   256
#define KCODES 8192
#define NROWS  32768
#define SPLITS 8           // code-splits; split = bid & 7 -> one split per XCD
#define CPB    1024        // codes per block = KCODES / SPLITS
#define NSB    32          // sub-blocks of 32 codes per block

typedef _Float16 f16x8 __attribute__((ext_vector_type(8)));
typedef float    f32x4 __attribute__((ext_vector_type(4)));
typedef unsigned long long u64;

// ---- async global->LDS, 16B per lane; LDS dest = wave-uniform base + lane*16 ----
__device__ __forceinline__ void load16_to_lds(const void* g, void* s) {
    __builtin_amdgcn_global_load_lds(
        (const __attribute__((address_space(1))) void*)(uintptr_t)g,
        (__attribute__((address_space(3))) void*)(uintptr_t)s,
        16, 0, 0);
}

// u64 branch-free top-4 insert
__device__ __forceinline__ void ins4(u64 c, u64 k[4]) {
    u64 a;
    a = k[0] > c ? k[0] : c;  c = k[0] > c ? c : k[0];  k[0] = a;
    a = k[1] > c ? k[1] : c;  c = k[1] > c ? c : k[1];  k[1] = a;
    a = k[2] > c ? k[2] : c;  c = k[2] > c ? c : k[2];  k[2] = a;
    k[3] = k[3] > c ? k[3] : c;
}

__device__ __forceinline__ uint32_t umin_(uint32_t a, uint32_t b) { return a < b ? a : b; }
__device__ __forceinline__ uint32_t umax_(uint32_t a, uint32_t b) { return a > b ? a : b; }

// =============== Kernel 1a: transpose x -> xh fp16 [N][C] + xt fp32 [N][C] ====
__global__ __launch_bounds__(256) void split_x_kernel(const float* __restrict__ x,
                                                      _Float16* __restrict__ xh,
                                                      float* __restrict__ xt) {
    __shared__ float tile[64][65];
    int pb = blockIdx.x, cbk = blockIdx.y, b = blockIdx.z;
    int t = threadIdx.x;
    int p0 = pb * 64, c0 = cbk * 64;
    int pl = t & 63, cl = t >> 6;
    const float* src = x + ((size_t)b * CDIM + c0) * HWP + p0;
    #pragma unroll 4
    for (int i = 0; i < 16; ++i) {
        int c = cl * 16 + i;
        tile[c][pl] = src[(size_t)c * HWP + pl];
    }
    __syncthreads();
    int p = t >> 2, cq = (t & 3) * 16;
    size_t n = (size_t)b * HWP + p0 + p;
    alignas(16) _Float16 hbuf[16];
    alignas(16) float    fbuf[16];
    #pragma unroll
    for (int j = 0; j < 16; ++j) {
        float v = tile[cq + j][p];
        fbuf[j] = v;
        hbuf[j] = (_Float16)v;
    }
    *(int4*)(xh + n * CDIM + c0 + cq)     = ((int4*)hbuf)[0];
    *(int4*)(xh + n * CDIM + c0 + cq + 8) = ((int4*)hbuf)[1];
    #pragma unroll
    for (int j = 0; j < 4; ++j)
        *(float4*)(xt + n * CDIM + c0 + cq + j * 4) = ((float4*)fbuf)[j];
}

// =============== Kernel 1b: convert codebook [K][C] -> fp16 ===================
__global__ __launch_bounds__(256) void split_cb_kernel(const float* __restrict__ cb,
                                                       _Float16* __restrict__ ch) {
    int i4 = blockIdx.x * 256 + threadIdx.x;          // 2048 blocks
    float4 v = ((const float4*)cb)[i4];
    alignas(8) _Float16 h[4];
    h[0] = (_Float16)v.x; h[1] = (_Float16)v.y;
    h[2] = (_Float16)v.z; h[3] = (_Float16)v.w;
    *(uint2*)(ch + (size_t)i4 * 4) = *(uint2*)h;
}

// =============== Kernel 2: A-in-registers fp16 MFMA GEMM, B streamed ==========
// Structure: ROUND-4 (measured 151.6 us) -- 2 x 16 KB double-buffered LDS,
// one full-drain __syncthreads per sub-block.
//
// ROUND-8 KEY PATH (fixes round-6's resolution bug, keeps its VALU savings):
// - acc init = 4608.0f: MFMA computes v+4608 for free. |partial| <= 361 < 512
//   keeps every intermediate in binade [4096,8192); bias rounding <=~1e-3,
//   an order below the fp16-input error; exact rescore absorbs it.
// - key = (bits(acc) << 10) | tag  (u32, PROVEN round-4 scheme, resolution
//   1 ulp = 4.9e-4. Round-6's mantissa-MASK key had resolution 1024 ulp =
//   0.5 -> evicted true winners -> absmax 3.71. The shift, not the mask, is
//   load-bearing.)
// - u32 top-2 insert: k2' = max(k2, min(k1, p)); k1' = max(k1, p)
//   (exact given k1>=k2; LLVM fuses to v_med3_u32). 4 VALU/key total.
// - cross-lane merge: K2' = max(min(K1,o1), max(K2,o2)) -- exact 2nd-max
//   of union; K1' = max(K1,o1).
__global__ __launch_bounds__(256, 2) void gemm_kernel(const _Float16* __restrict__ xh,
                                                      const _Float16* __restrict__ ch,
                                                      uint2* __restrict__ ptop) {
    __shared__ _Float16 sB[2][32 * CDIM];          // 2 x 16 KB

    int t = threadIdx.x;
    int w = t >> 6, lane = t & 63;
    int cc2 = lane & 15, qq = lane >> 4;
    int bid = blockIdx.x;
    int split  = bid & 7;
    int rowblk = bid >> 3;
    int rw = rowblk * 256 + w * 64;                // wave row base
    int c0 = split * CPB;                          // code base

    // ---- A fragments: full K in registers (4 mi x 8 ks x f16x8) -------------
    f16x8 a[4][8];
    {
        const _Float16* ap = xh + (size_t)(rw + cc2) * CDIM + qq * 8;
        #pragma unroll
        for (int mi = 0; mi < 4; ++mi)
            #pragma unroll
            for (int ks = 0; ks < 8; ++ks)
                a[mi][ks] = *(const f16x8*)(ap + (size_t)(mi * 16) * CDIM + ks * 32);
    }

    // ---- staging geometry (slot-permuted, pre-swizzled global source) -------
    const int u_ = t >> 5;                         // 0..7
    const _Float16* sbs[4];
    #pragma unroll
    for (int it = 0; it < 4; ++it) {
        int rot   = it * 2 + (u_ >> 2);            // sigma>>2  (0..7)
        int wcode = ((u_ & 1) << 4) | (((u_ >> 1) & 1) << 3) | rot;
        int j     = (t & 31) ^ rot;
        sbs[it] = ch + (size_t)(c0 + wcode) * CDIM + j * 8;
    }
    char* dst0 = (char*)&sB[0][0] + (w * 64) * 16;
    char* dst1 = (char*)&sB[1][0] + (w * 64) * 16;

    // prologue: stage sub-block 0 into buffer 0 (A loads drain here too)
    #pragma unroll
    for (int it = 0; it < 4; ++it)
        load16_to_lds(sbs[it], dst0 + it * 4096);
    __syncthreads();

    // read-side lane constants
    const int sig2 = (cc2 & 7) * 4 + ((cc2 >> 3) << 1);   // sigma minus ni
    const int gx   = cc2 & 7;                             // xor spread
    const uint32_t tbase = (uint32_t)(1023 - ((cc2 >> 3) * 8 + (cc2 & 7)));

    uint32_t k1[4][4], k2[4][4];
    #pragma unroll
    for (int mi = 0; mi < 4; ++mi)
        #pragma unroll
        for (int r = 0; r < 4; ++r) { k1[mi][r] = 0u; k2[mi][r] = 0u; }

    const f32x4 init4608 = {4608.0f, 4608.0f, 4608.0f, 4608.0f};

    #pragma unroll 2
    for (int s = 0; s < NSB; ++s) {
        // issue next sub-block's DMA now; it overlaps this sub-block's MFMAs
        if (s < NSB - 1) {
            size_t soff = (size_t)(s + 1) * (32 * CDIM);
            char* dst = (s & 1) ? dst0 : dst1;
            #pragma unroll
            for (int it = 0; it < 4; ++it)
                load16_to_lds(sbs[it] + soff, dst + it * 4096);
        }

        const char* bufB = (const char*)&sB[s & 1][0];
        f32x4 acc[2][4];
        #pragma unroll
        for (int ni = 0; ni < 2; ++ni)
            #pragma unroll
            for (int mi = 0; mi < 4; ++mi) acc[ni][mi] = init4608;

        #pragma unroll
        for (int ks = 0; ks < 8; ++ks) {
            int g = (ks * 4 + qq) ^ gx;
            const char* bb = bufB + sig2 * 512 + g * 16;
            f16x8 bf0 = *(const f16x8*)(bb);
            f16x8 bf1 = *(const f16x8*)(bb + 512);
            acc[0][0] = __builtin_amdgcn_mfma_f32_16x16x32_f16(a[0][ks], bf0, acc[0][0], 0, 0, 0);
            acc[0][1] = __builtin_amdgcn_mfma_f32_16x16x32_f16(a[1][ks], bf0, acc[0][1], 0, 0, 0);
            acc[0][2] = __builtin_amdgcn_mfma_f32_16x16x32_f16(a[2][ks], bf0, acc[0][2], 0, 0, 0);
            acc[0][3] = __builtin_amdgcn_mfma_f32_16x16x32_f16(a[3][ks], bf0, acc[0][3], 0, 0, 0);
            acc[1][0] = __builtin_amdgcn_mfma_f32_16x16x32_f16(a[0][ks], bf1, acc[1][0], 0, 0, 0);
            acc[1][1] = __builtin_amdgcn_mfma_f32_16x16x32_f16(a[1][ks], bf1, acc[1][1], 0, 0, 0);
            acc[1][2] = __builtin_amdgcn_mfma_f32_16x16x32_f16(a[2][ks], bf1, acc[1][2], 0, 0, 0);
            acc[1][3] = __builtin_amdgcn_mfma_f32_16x16x32_f16(a[3][ks], bf1, acc[1][3], 0, 0, 0);
        }

        // u32 shift-keys; insert: k2' = max(k2, min(k1,p)), k1' = max(k1,p)
        uint32_t tag0 = tbase - (uint32_t)(s * 32);
        uint32_t tag1 = tag0 - 16u;
        #pragma unroll
        for (int mi = 0; mi < 4; ++mi)
            #pragma unroll
            for (int r = 0; r < 4; ++r) {
                uint32_t key0 = (__float_as_uint(acc[0][mi][r]) << 10) | tag0;
                uint32_t key1 = (__float_as_uint(acc[1][mi][r]) << 10) | tag1;
                uint32_t K1 = k1[mi][r], K2 = k2[mi][r];
                K2 = umax_(K2, umin_(K1, key0));
                K1 = umax_(K1, key0);
                K2 = umax_(K2, umin_(K1, key1));
                K1 = umax_(K1, key1);
                k1[mi][r] = K1;
                k2[mi][r] = K2;
            }
        __syncthreads();   // next iter's DMA overwrites the buffer just read
    }

    // cross-lane (16-code columns) top-2 merge + write one uint2 per row
    #pragma unroll
    for (int mi = 0; mi < 4; ++mi)
        #pragma unroll
        for (int r = 0; r < 4; ++r) {
            uint32_t K1 = k1[mi][r], K2 = k2[mi][r];
            #pragma unroll
            for (int msk = 1; msk <= 8; msk <<= 1) {
                uint32_t o1 = (uint32_t)__shfl_xor((int)K1, msk);
                uint32_t o2 = (uint32_t)__shfl_xor((int)K2, msk);
                K2 = umax_(umin_(K1, o1), umax_(K2, o2));
                K1 = umax_(K1, o1);
            }
            if (cc2 == 0) {
                int row = rw + mi * 16 + qq * 4 + r;
                ptop[(size_t)split * NROWS + row] = make_uint2(K1, K2);
            }
        }
}

// =============== Kernel 3: fused finalize = reduce + rescore + writeq =========
__global__ __launch_bounds__(256) void finalize_kernel(const uint2* __restrict__ ptop,
                                                       const float* __restrict__ xt,
                                                       const float* __restrict__ cb,
                                                       float* __restrict__ loss_sum,
                                                       unsigned* __restrict__ counter,
                                                       float* __restrict__ out) {
    __shared__ int4  scand[64];
    __shared__ int   swin[64];
    __shared__ float rows[64][260];       // pad 260 (16B-aligned rows)

    int bh = blockIdx.x;                  // b*64 + h
    int b = bh >> 6, h = bh & 63;
    int t = threadIdx.x;

    // ---- phase 1: per-row top-4 over 8 splits ----
    if (t < 64) {
        int n = bh * 64 + t;
        u64 k[4] = {0ull, 0ull, 0ull, 0ull};
        #pragma unroll
        for (int sp = 0; sp < SPLITS; ++sp) {
            uint2 e = ptop[(size_t)sp * NROWS + n];
            ins4(((u64)e.x << 3) | (unsigned)sp, k);
            ins4(((u64)e.y << 3) | (unsigned)sp, k);
        }
        int4 c4;
        int cc[4];
        #pragma unroll
        for (int j = 0; j < 4; ++j) {
            int sp       = (int)(k[j] & 7u);
            uint32_t key = (uint32_t)(k[j] >> 3);
            cc[j] = sp * CPB + 1023 - (int)(key & 1023u);
        }
        c4.x = cc[0]; c4.y = cc[1]; c4.z = cc[2]; c4.w = cc[3];
        scand[t] = c4;
    }
    __syncthreads();

    // ---- phase 2: exact rescore, 4 chunks of 16 rows ----
    int l = t & 63;
    int cl = t & 15;
    float lpacc = 0.f;
    for (int chunk = 0; chunk < 4; ++chunk) {
        int rloc = chunk * 16 + (t >> 4);
        int n = bh * 64 + rloc;
        int4 cd = scand[rloc];
        const float* xr = xt + (size_t)n * CDIM + cl * 16;
        const float* r0 = cb + (size_t)cd.x * CDIM + cl * 16;
        const float* r1 = cb + (size_t)cd.y * CDIM + cl * 16;
        const float* r2 = cb + (size_t)cd.z * CDIM + cl * 16;
        const float* r3 = cb + (size_t)cd.w * CDIM + cl * 16;
        float n2 = 0.f, d0 = 0.f, d1 = 0.f, d2 = 0.f, d3 = 0.f;
        #pragma unroll
        for (int chk = 0; chk < 4; ++chk) {
            float4 xv = *(const float4*)(xr + chk * 4);
            float4 a0 = *(const float4*)(r0 + chk * 4);
            float4 a1 = *(const float4*)(r1 + chk * 4);
            float4 a2 = *(const float4*)(r2 + chk * 4);
            float4 a3 = *(const float4*)(r3 + chk * 4);
            float xs[4] = {xv.x, xv.y, xv.z, xv.w};
            float b0[4] = {a0.x, a0.y, a0.z, a0.w};
            float b1[4] = {a1.x, a1.y, a1.z, a1.w};
            float b2[4] = {a2.x, a2.y, a2.z, a2.w};
            float b3[4] = {a3.x, a3.y, a3.z, a3.w};
            #pragma unroll
            for (int j = 0; j < 4; ++j) {
                n2 = fmaf(xs[j], xs[j], n2);
                d0 = fmaf(xs[j], b0[j], d0);
                d1 = fmaf(xs[j], b1[j], d1);
                d2 = fmaf(xs[j], b2[j], d2);
                d3 = fmaf(xs[j], b3[j], d3);
            }
        }
        #pragma unroll
        for (int m = 1; m <= 8; m <<= 1) {
            n2 += __shfl_xor(n2, m);
            d0 += __shfl_xor(d0, m);
            d1 += __shfl_xor(d1, m);
            d2 += __shfl_xor(d2, m);
            d3 += __shfl_xor(d3, m);
        }
        if (cl == 0) {
            float bD = d0; int bI = cd.x;
            if (d1 > bD || (d1 == bD && cd.y < bI)) { bD = d1; bI = cd.y; }
            if (d2 > bD || (d2 == bD && cd.z < bI)) { bD = d2; bI = cd.z; }
            if (d3 > bD || (d3 == bD && cd.w < bI)) { bD = d3; bI = cd.w; }
            swin[rloc] = bI;
            lpacc += bD / fmaxf(sqrtf(n2), 1e-12f);
        }
    }
    #pragma unroll
    for (int m = 1; m <= 32; m <<= 1) lpacc += __shfl_xor(lpacc, m);
    if (l == 0) atomicAdd(loss_sum, lpacc);
    __syncthreads();

    // ---- phase 3: gather q via LDS transpose + coalesced write ----
    int rr = t >> 6, cq = t & 63;
    #pragma unroll 4
    for (int i = 0; i < 16; ++i) {
        int wv = i * 4 + rr;
        int id = swin[wv];
        float4 v = *(const float4*)(cb + (size_t)id * CDIM + cq * 4);
        *(float4*)&rows[wv][cq * 4] = v;
    }
    __syncthreads();
    int wl = t & 63, cg = t >> 6;
    float* ob = out + (size_t)b * CDIM * HWP + h * 64 + wl;
    #pragma unroll 4
    for (int c = cg * 64; c < cg * 64 + 64; ++c)
        ob[(size_t)c * HWP] = rows[wl][c];

    // ---- last block writes the two loss scalars ----
    __syncthreads();
    if (t == 0) {
        __threadfence();
        unsigned prev = atomicAdd(counter, 1u);
        if (prev == 511u) {
            float total = atomicAdd(loss_sum, 0.0f);   // coherent read
            float mean = total / 32768.0f;
            out[8388608] = 0.25f * (1.0f - mean);
            out[8388609] = 1.0f  * (1.0f - mean);
        }
    }
}

extern "C" void kernel_launch(void* const* d_in, const int* in_sizes, int n_in,
                              void* d_out, int out_size, void* d_ws, size_t ws_size,
                              hipStream_t stream) {
    const float* x  = (const float*)d_in[0];   // [8,256,64,64]
    const float* cb = (const float*)d_in[1];   // [8192,256]
    float* out = (float*)d_out;

    char* ws = (char*)d_ws;
    _Float16* xh   = (_Float16*)(ws);                     // 16,777,216 B
    _Float16* ch   = (_Float16*)(ws + 16777216);          //  4,194,304 B
    float*    xt   = (float*)   (ws + 20971520);          // 33,554,432 B
    uint2*    ptop = (uint2*)   (ws + 54525952);          //  2,097,152 B
    float*    loss = (float*)   (ws + 71958528);          //          4 B
    unsigned* cnt  = (unsigned*)(ws + 71958532);          //          4 B

    hipMemsetAsync(loss, 0, 8, stream);                   // loss + counter
    split_x_kernel <<<dim3(64, 4, 8), 256, 0, stream>>>(x, xh, xt);
    split_cb_kernel<<<2048,           256, 0, stream>>>(cb, ch);
    gemm_kernel    <<<1024,           256, 0, stream>>>(xh, ch, ptop);
    finalize_kernel<<<512,            256, 0, stream>>>(ptop, xt, cb, loss, cnt, out);
}